// Round 9
// baseline (441.298 us; speedup 1.0000x reference)
//
#include <hip/hip_runtime.h>

// GCN: N=100000 nodes, E=1600000 edges, F_IN=F_HID=64, F_OUT=16, fp32.
//
// Reformulation:
//   pairnorm(x) @ W = (x @ W) * rinv_row - (colmean(x) @ W)
//   graph_conv(h)   = gather_dst(z[src]) + z + b,  where z = h @ W
//
// R8 -> R9: gather64 still latency-bound (43 us, VALU 22%, HBM 34%) and ~200us
// of the 437 total is inter-dispatch gap (13 dispatches). (1) Dual-node waves:
// 2 interleaved 8-deep load streams -> up to 32 rows in flight; grid-stride
// 2048 blocks. (2) ReLU + layer-2 colsum fused into gather64 epilogue
// (colsum2 dispatch deleted); colsum1 merged into countA (prelude). 11 disp.

#define NHB 64      // max hi-buckets (supports N <= 131072); hi = dst >> 11

__device__ __forceinline__ unsigned short f2bf(float f) {
  unsigned u = __builtin_bit_cast(unsigned, f);
  u += 0x7FFFu + ((u >> 16) & 1u);    // round-to-nearest-even
  return (unsigned short)(u >> 16);
}
__device__ __forceinline__ float bf2f(unsigned short h) {
  return __builtin_bit_cast(float, ((unsigned)h) << 16);
}

// ------- prelude: cntA histogram of dst (hi-buckets) + column sums of feat -------
__global__ __launch_bounds__(256) void prelude_kernel(
    const int* __restrict__ dst, int* __restrict__ cntA, int E,
    const float* __restrict__ x, float* __restrict__ cs, int n4) {
  __shared__ int lc[NHB];
  __shared__ float lds[16][64];
  const int t = threadIdx.x;
  if (t < NHB) lc[t] = 0;
  __syncthreads();
  const int stride = gridDim.x * blockDim.x;
  for (int e = blockIdx.x * blockDim.x + t; e < E; e += stride)
    atomicAdd(&lc[__builtin_nontemporal_load(&dst[e]) >> 11], 1);

  float s0 = 0.f, s1 = 0.f, s2 = 0.f, s3 = 0.f;
  for (int i = blockIdx.x * blockDim.x + t; i < n4; i += stride) {
    float4 v = ((const float4*)x)[i];
    s0 += v.x; s1 += v.y; s2 += v.z; s3 += v.w;
  }
  const int r = t >> 4;
  const int cq = (t & 15) * 4;
  lds[r][cq + 0] = s0; lds[r][cq + 1] = s1; lds[r][cq + 2] = s2; lds[r][cq + 3] = s3;
  __syncthreads();
  if (t < NHB && lc[t]) atomicAdd(&cntA[t], lc[t]);
  if (t < 64) {
    float tot = 0.f;
    #pragma unroll
    for (int rr = 0; rr < 16; ++rr) tot += lds[rr][t];
    unsafeAtomicAdd(&cs[t], tot);
  }
}

// ------------- fused: z = (x @ W) * rinv - cmW, bf16 out -------------
// x arrives pre-relu'd (gather64 writes relu'd agg). cm computed during staging.
__global__ __launch_bounds__(256) void matnorm_kernel(
    const float* x, const float* __restrict__ W,
    const float* __restrict__ cs, unsigned short* __restrict__ z,
    int N, float invN) {
  const int lane = threadIdx.x & 63;
  const int wid  = blockIdx.x * (blockDim.x >> 6) + (threadIdx.x >> 6);
  const int nw   = gridDim.x * (blockDim.x >> 6);

  float w[64];
  float cm = 0.f;
  #pragma unroll
  for (int k = 0; k < 64; ++k) {
    w[k] = W[k * 64 + lane];
    cm = fmaf(cs[k], w[k], cm);    // cs[k] uniform scalar load
  }
  cm *= invN;

  for (int row = wid; row < N; row += nw) {
    const float xv = x[(size_t)row * 64 + lane];
    float ss = xv * xv;
    #pragma unroll
    for (int m = 1; m < 64; m <<= 1) ss += __shfl_xor(ss, m, 64);
    const float rinv = 1.0f / sqrtf(1e-6f + ss);
    float acc = 0.f;
    #pragma unroll
    for (int k = 0; k < 64; ++k) {
      const float xk = __builtin_bit_cast(
          float, __builtin_amdgcn_readlane(__builtin_bit_cast(int, xv), k));
      acc = fmaf(xk, w[k], acc);
    }
    z[(size_t)row * 64 + lane] = f2bf(acc * rinv - cm);
  }
}

// ------------- layer 3: z3 = x @ W3 (64->16), bf16 out (x pre-relu'd) -------------
__global__ __launch_bounds__(256) void mat16_kernel(
    const float* __restrict__ x, const float* __restrict__ W3,
    unsigned short* __restrict__ z3, int N) {
  const int lane = threadIdx.x & 63;
  const int j = lane & 15;
  const int wid = blockIdx.x * (blockDim.x >> 6) + (threadIdx.x >> 6);
  const int nw  = gridDim.x * (blockDim.x >> 6);

  float w[64];
  #pragma unroll
  for (int k = 0; k < 64; ++k) w[k] = W3[k * 16 + j];
  for (int row = wid; row < N; row += nw) {
    const float xv = x[(size_t)row * 64 + lane];
    float acc = 0.f;
    #pragma unroll
    for (int k = 0; k < 64; ++k) {
      const float xk = __builtin_bit_cast(
          float, __builtin_amdgcn_readlane(__builtin_bit_cast(int, xv), k));
      acc = fmaf(xk, w[k], acc);
    }
    if (lane < 16) z3[(size_t)row * 16 + lane] = f2bf(acc);
  }
}

// ================= CSR build: hi-bucket radix + LDS counting sort =================

__global__ void scanA_kernel(const int* __restrict__ cntA,
                             int* __restrict__ baseA, int* __restrict__ curA,
                             int NHI) {
  if (threadIdx.x == 0) {
    int acc = 0;
    for (int p = 0; p < NHI; ++p) { baseA[p] = acc; curA[p] = acc; acc += cntA[p]; }
    baseA[NHI] = acc;
  }
}

#define TILE 2048
#define CAPA 96   // per-tile per-bucket mean 42, sigma 6.4 -> 8.5 sigma headroom + spill
__global__ __launch_bounds__(256) void scatterA_kernel(
    const int* __restrict__ src, const int* __restrict__ dst,
    int* __restrict__ curA, int* __restrict__ psrc, int* __restrict__ pdst,
    int E) {
  __shared__ int lss[NHB][CAPA], ldd[NHB][CAPA];
  __shared__ int lcnt[NHB], lbase[NHB];
  const int t = threadIdx.x;
  if (t < NHB) lcnt[t] = 0;
  __syncthreads();
  const int ntiles = (E + TILE - 1) / TILE;
  for (int tile = blockIdx.x; tile < ntiles; tile += gridDim.x) {
    const int base = tile * TILE;
    #pragma unroll
    for (int j = 0; j < TILE / 256; ++j) {
      const int e = base + j * 256 + t;   // coalesced
      if (e < E) {
        const int d = __builtin_nontemporal_load(&dst[e]);
        const int s = __builtin_nontemporal_load(&src[e]);
        const int p = d >> 11;
        const int slot = atomicAdd(&lcnt[p], 1);
        if (slot < CAPA) { lss[p][slot] = s; ldd[p][slot] = d; }
        else {  // rare spill
          const int pos = atomicAdd(&curA[p], 1);
          psrc[pos] = s; pdst[pos] = d;
        }
      }
    }
    __syncthreads();
    if (t < NHB) {
      int c = lcnt[t]; if (c > CAPA) c = CAPA;
      lbase[t] = c ? atomicAdd(&curA[t], c) : 0;
      lcnt[t] = c;
    }
    __syncthreads();
    for (int p = 0; p < NHB; ++p) {
      const int c = lcnt[p];
      if (t < c) {  // c <= 96 < 256: one step, contiguous chunk
        psrc[lbase[p] + t] = lss[p][t];
        pdst[lbase[p] + t] = ldd[p][t];
      }
    }
    __syncthreads();
    if (t < NHB) lcnt[t] = 0;
    __syncthreads();
  }
}

// One workgroup (1024 thr) per hi-bucket: LDS counting sort of its ~32.7K
// edges by exact dst, coalesced csr + rowstart writes, 131 KB window on 1 CU.
__global__ __launch_bounds__(1024) void fillsort_kernel(
    const int* __restrict__ psrc, const int* __restrict__ pdst,
    const int* __restrict__ baseA, int* __restrict__ rowstart,
    int* __restrict__ csr, int N, int E) {
  __shared__ int hist[2048];
  __shared__ int bs[1024];
  const int t = threadIdx.x;
  const int h = blockIdx.x;
  const int nlo = h << 11;
  const int elo = baseA[h], ehi = baseA[h + 1];

  for (int i = t; i < 2048; i += 1024) hist[i] = 0;
  __syncthreads();

  // phase 1: histogram (4 independent loads in flight)
  int e = elo + t;
  for (; e + 3 * 1024 < ehi; e += 4 * 1024) {
    const int d0 = pdst[e], d1 = pdst[e + 1024],
              d2 = pdst[e + 2048], d3 = pdst[e + 3072];
    atomicAdd(&hist[d0 - nlo], 1); atomicAdd(&hist[d1 - nlo], 1);
    atomicAdd(&hist[d2 - nlo], 1); atomicAdd(&hist[d3 - nlo], 1);
  }
  for (; e < ehi; e += 1024) atomicAdd(&hist[pdst[e] - nlo], 1);
  __syncthreads();

  // exclusive scan of hist[2048] (2 per thread + 1024-wide Hillis-Steele)
  const int c0 = hist[2 * t], c1 = hist[2 * t + 1];
  const int s = c0 + c1;
  bs[t] = s;
  __syncthreads();
  for (int off = 1; off < 1024; off <<= 1) {
    const int v = (t >= off) ? bs[t - off] : 0;
    __syncthreads();
    bs[t] += v;
    __syncthreads();
  }
  const int excl = bs[t] - s;

  // rowstart + LDS cursors
  const int n0 = nlo + 2 * t;
  hist[2 * t] = excl;
  hist[2 * t + 1] = excl + c0;
  if (n0 < N)     rowstart[n0]     = elo + excl;
  if (n0 + 1 < N) rowstart[n0 + 1] = elo + excl + c0;
  if (h == 0 && t == 0) rowstart[N] = E;
  __syncthreads();

  // phase 2: place (all csr writes land in this bucket's 131 KB window)
  e = elo + t;
  for (; e + 3 * 1024 < ehi; e += 4 * 1024) {
    const int d0 = pdst[e],        s0 = psrc[e];
    const int d1 = pdst[e + 1024], s1 = psrc[e + 1024];
    const int d2 = pdst[e + 2048], s2 = psrc[e + 2048];
    const int d3 = pdst[e + 3072], s3 = psrc[e + 3072];
    csr[elo + atomicAdd(&hist[d0 - nlo], 1)] = s0;
    csr[elo + atomicAdd(&hist[d1 - nlo], 1)] = s1;
    csr[elo + atomicAdd(&hist[d2 - nlo], 1)] = s2;
    csr[elo + atomicAdd(&hist[d3 - nlo], 1)] = s3;
  }
  for (; e < ehi; e += 1024) {
    const int d = pdst[e], sv = psrc[e];
    csr[elo + atomicAdd(&hist[d - nlo], 1)] = sv;
  }
}

// ------- gather64: agg[d] = relu(z[d] + b + sum z[src]); dual-node waves -------
// Two interleaved 8-deep load streams (up to 32 rows in flight). Optional
// fused column-sum (csg != nullptr) via block LDS reduce + 64 atomics/block.
__global__ __launch_bounds__(256) void gather64_kernel(
    const unsigned short* __restrict__ z, const float* __restrict__ b,
    const int* __restrict__ rowstart, const int* __restrict__ csr,
    float* __restrict__ agg, float* __restrict__ csg, int N) {
  const int lane = threadIdx.x & 63;
  const int wid  = blockIdx.x * (blockDim.x >> 6) + (threadIdx.x >> 6);
  const int nw   = gridDim.x * (blockDim.x >> 6);
  const float bl = b[lane];
  float csum = 0.f;
  const int npair = (N + 1) >> 1;

  for (int p = wid; p < npair; p += nw) {
    const int n0 = __builtin_amdgcn_readfirstlane(2 * p);
    const int hasB = (n0 + 1 < N);
    const int sA   = rowstart[n0];
    const int eAend = rowstart[n0 + 1];
    const int eBend = hasB ? rowstart[n0 + 2] : eAend;
    const unsigned short hsA = z[(size_t)n0 * 64 + lane];
    const unsigned short hsB = z[(size_t)(n0 + hasB) * 64 + lane];
    float a0 = 0.f, a1 = 0.f, a2 = 0.f, a3 = 0.f;
    float c0 = 0.f, c1 = 0.f, c2 = 0.f, c3 = 0.f;
    int eA = sA, eB = eAend;
    // joint phase: 8+8 independent loads per iteration
    while (eA + 8 <= eAend && eB + 8 <= eBend) {
      unsigned short hA[8], hB[8];
      #pragma unroll
      for (int j = 0; j < 8; ++j) hA[j] = z[(size_t)csr[eA + j] * 64 + lane];
      #pragma unroll
      for (int j = 0; j < 8; ++j) hB[j] = z[(size_t)csr[eB + j] * 64 + lane];
      #pragma unroll
      for (int j = 0; j < 8; j += 4) {
        a0 += bf2f(hA[j]); a1 += bf2f(hA[j + 1]);
        a2 += bf2f(hA[j + 2]); a3 += bf2f(hA[j + 3]);
        c0 += bf2f(hB[j]); c1 += bf2f(hB[j + 1]);
        c2 += bf2f(hB[j + 2]); c3 += bf2f(hB[j + 3]);
      }
      eA += 8; eB += 8;
    }
    // drain A
    for (; eA + 8 <= eAend; eA += 8) {
      unsigned short hA[8];
      #pragma unroll
      for (int j = 0; j < 8; ++j) hA[j] = z[(size_t)csr[eA + j] * 64 + lane];
      #pragma unroll
      for (int j = 0; j < 8; j += 4) {
        a0 += bf2f(hA[j]); a1 += bf2f(hA[j + 1]);
        a2 += bf2f(hA[j + 2]); a3 += bf2f(hA[j + 3]);
      }
    }
    for (; eA < eAend; ++eA) a0 += bf2f(z[(size_t)csr[eA] * 64 + lane]);
    // drain B
    for (; eB + 8 <= eBend; eB += 8) {
      unsigned short hB[8];
      #pragma unroll
      for (int j = 0; j < 8; ++j) hB[j] = z[(size_t)csr[eB + j] * 64 + lane];
      #pragma unroll
      for (int j = 0; j < 8; j += 4) {
        c0 += bf2f(hB[j]); c1 += bf2f(hB[j + 1]);
        c2 += bf2f(hB[j + 2]); c3 += bf2f(hB[j + 3]);
      }
    }
    for (; eB < eBend; ++eB) c0 += bf2f(z[(size_t)csr[eB] * 64 + lane]);

    const float oA = fmaxf(bf2f(hsA) + bl + ((a0 + a1) + (a2 + a3)), 0.f);
    agg[(size_t)n0 * 64 + lane] = oA;
    csum += oA;
    if (hasB) {
      const float oB = fmaxf(bf2f(hsB) + bl + ((c0 + c1) + (c2 + c3)), 0.f);
      agg[(size_t)(n0 + 1) * 64 + lane] = oB;
      csum += oB;
    }
  }

  if (csg) {   // fused column sums for the next layer's pairnorm
    __shared__ float lcs[4][64];
    const int w = threadIdx.x >> 6;
    lcs[w][lane] = csum;
    __syncthreads();
    if (threadIdx.x < 64) {
      unsafeAtomicAdd(&csg[threadIdx.x],
                      lcs[0][threadIdx.x] + lcs[1][threadIdx.x] +
                      lcs[2][threadIdx.x] + lcs[3][threadIdx.x]);
    }
  }
}

// ------- gather16: out[d] = z3[d] + b3 + sum z3[src]; 16 feat x 4 edge-groups -------
__global__ __launch_bounds__(256) void gather16_kernel(
    const unsigned short* __restrict__ z3, const float* __restrict__ b3,
    const int* __restrict__ rowstart, const int* __restrict__ csr,
    float* __restrict__ out, int N) {
  const int lane = threadIdx.x & 63;
  const int f = lane & 15;
  const int g = lane >> 4;
  int node = blockIdx.x * (blockDim.x >> 6) + (threadIdx.x >> 6);
  if (node >= N) return;
  node = __builtin_amdgcn_readfirstlane(node);
  const int start = rowstart[node];
  const int end   = rowstart[node + 1];
  float acc0 = 0.f, acc1 = 0.f;
  int e = start + g;
  for (; e + 4 < end; e += 8) {      // 2 outstanding per lane-group
    acc0 += bf2f(z3[(size_t)csr[e] * 16 + f]);
    acc1 += bf2f(z3[(size_t)csr[e + 4] * 16 + f]);
  }
  if (e < end) acc0 += bf2f(z3[(size_t)csr[e] * 16 + f]);
  float acc = acc0 + acc1;
  acc += __shfl_xor(acc, 16, 64);
  acc += __shfl_xor(acc, 32, 64);
  if (lane < 16)
    out[(size_t)node * 16 + f] = bf2f(z3[(size_t)node * 16 + f]) + b3[f] + acc;
}

extern "C" void kernel_launch(void* const* d_in, const int* in_sizes, int n_in,
                              void* d_out, int out_size, void* d_ws, size_t ws_size,
                              hipStream_t stream) {
  const float* feat = (const float*)d_in[0];
  const float* W1 = (const float*)d_in[1];
  const float* b1 = (const float*)d_in[2];
  const float* W2 = (const float*)d_in[3];
  const float* b2 = (const float*)d_in[4];
  const float* W3 = (const float*)d_in[5];
  const float* b3 = (const float*)d_in[6];
  const int* src = (const int*)d_in[7];
  const int* dst = (const int*)d_in[8];
  const int N = in_sizes[0] / 64;
  const int E = in_sizes[7];
  float* out = (float*)d_out;

  // workspace layout
  float* B            = (float*)d_ws;                     // agg, N*64 fp32
  unsigned short* zb  = (unsigned short*)(B + (size_t)N * 64);  // z, N*64 bf16
  unsigned short* z3b = zb + (size_t)N * 64;              // z3, N*16 bf16
  int* cntA  = (int*)(z3b + (size_t)N * 16);              // NHB       } one memset
  float* cs1 = (float*)(cntA + NHB);                      // 64        } covers
  float* cs2 = cs1 + 64;                                  // 64        } these 3
  int* baseA    = (int*)(cs2 + 64);                       // NHB+1
  int* curA     = baseA + NHB + 1;                        // NHB
  int* rowstart = curA + NHB;                             // N+1
  int* csr      = rowstart + N + 1;                       // E
  // psrc/pdst alias zb+z3b (dead until matnorm/mat16): 2E ints = 12.8 MB <= 16 MB
  int* psrc = (int*)zb;
  int* pdst = psrc + E;

  const int NHI = (N + 2047) >> 11;     // 49
  const int node_blocks = (N + 3) / 4;  // gather16: 4 waves of 64 per block
  const float invN = 1.0f / (float)N;

  // ---- CSR build + layer-1 colsum ----
  hipMemsetAsync(cntA, 0, (NHB + 128) * sizeof(int), stream);  // cntA + cs1 + cs2
  prelude_kernel<<<512, 256, 0, stream>>>(dst, cntA, E, feat, cs1, N * 16);
  scanA_kernel<<<1, 64, 0, stream>>>(cntA, baseA, curA, NHI);
  scatterA_kernel<<<512, 256, 0, stream>>>(src, dst, curA, psrc, pdst, E);
  fillsort_kernel<<<NHI, 1024, 0, stream>>>(psrc, pdst, baseA, rowstart, csr, N, E);

  // ---- layer 1 (gather writes relu'd agg + colsum for layer 2) ----
  matnorm_kernel<<<1024, 256, 0, stream>>>(feat, W1, cs1, zb, N, invN);
  gather64_kernel<<<2048, 256, 0, stream>>>(zb, b1, rowstart, csr, B, cs2, N);

  // ---- layer 2 (B pre-relu'd; cs2 = colsum(relu(agg1))) ----
  matnorm_kernel<<<1024, 256, 0, stream>>>(B, W2, cs2, zb, N, invN);
  gather64_kernel<<<2048, 256, 0, stream>>>(zb, b2, rowstart, csr, B, nullptr, N);

  // ---- layer 3 (B pre-relu'd) ----
  mat16_kernel<<<1024, 256, 0, stream>>>(B, W3, z3b, N);
  gather16_kernel<<<node_blocks, 256, 0, stream>>>(z3b, b3, rowstart, csr, out, N);
}

// Round 10
// 425.982 us; speedup vs baseline: 1.0360x; 1.0360x over previous
//
#include <hip/hip_runtime.h>

// GCN: N=100000 nodes, E=1600000 edges, F_IN=F_HID=64, F_OUT=16, fp32.
//
// Reformulation:
//   pairnorm(x) @ W = (x @ W) * rinv_row - (colmean(x) @ W)
//   graph_conv(h)   = gather_dst(z[src]) + z + b,  where z = h @ W
//
// R9 -> R10: dual-node persistent gather REGRESSED (43 -> 81 us, issue rate
// halved): interleave only sustains 16-deep while both streams >=8 edges, and
// persistent waves serialize node-pairs. Revert to R8's proven gather64
// (one node/wave then exit, 16-deep flat ladder, uniform scalar base).
// Kept: prelude fusion, cm-fused matnorm, ReLU moved into gather64 store
// (colsum2/matnorm2/mat16 read pre-relu'd data).

#define NHB 64      // max hi-buckets (supports N <= 131072); hi = dst >> 11

__device__ __forceinline__ unsigned short f2bf(float f) {
  unsigned u = __builtin_bit_cast(unsigned, f);
  u += 0x7FFFu + ((u >> 16) & 1u);    // round-to-nearest-even
  return (unsigned short)(u >> 16);
}
__device__ __forceinline__ float bf2f(unsigned short h) {
  return __builtin_bit_cast(float, ((unsigned)h) << 16);
}

// ------- prelude: cntA histogram of dst (hi-buckets) + column sums of feat -------
__global__ __launch_bounds__(256) void prelude_kernel(
    const int* __restrict__ dst, int* __restrict__ cntA, int E,
    const float* __restrict__ x, float* __restrict__ cs, int n4) {
  __shared__ int lc[NHB];
  __shared__ float lds[16][64];
  const int t = threadIdx.x;
  if (t < NHB) lc[t] = 0;
  __syncthreads();
  const int stride = gridDim.x * blockDim.x;
  for (int e = blockIdx.x * blockDim.x + t; e < E; e += stride)
    atomicAdd(&lc[__builtin_nontemporal_load(&dst[e]) >> 11], 1);

  float s0 = 0.f, s1 = 0.f, s2 = 0.f, s3 = 0.f;
  for (int i = blockIdx.x * blockDim.x + t; i < n4; i += stride) {
    float4 v = ((const float4*)x)[i];
    s0 += v.x; s1 += v.y; s2 += v.z; s3 += v.w;
  }
  const int r = t >> 4;
  const int cq = (t & 15) * 4;
  lds[r][cq + 0] = s0; lds[r][cq + 1] = s1; lds[r][cq + 2] = s2; lds[r][cq + 3] = s3;
  __syncthreads();
  if (t < NHB && lc[t]) atomicAdd(&cntA[t], lc[t]);
  if (t < 64) {
    float tot = 0.f;
    #pragma unroll
    for (int rr = 0; rr < 16; ++rr) tot += lds[rr][t];
    unsafeAtomicAdd(&cs[t], tot);
  }
}

// ---------------- column sums of B (already relu'd by gather64) ----------------
__global__ void colsum_kernel(const float* __restrict__ x, float* __restrict__ cs,
                              int n4) {
  __shared__ float lds[16][64];
  float s0 = 0.f, s1 = 0.f, s2 = 0.f, s3 = 0.f;
  const int t = threadIdx.x;
  const int stride = gridDim.x * blockDim.x;
  for (int i = blockIdx.x * blockDim.x + t; i < n4; i += stride) {
    float4 v = ((const float4*)x)[i];
    s0 += v.x; s1 += v.y; s2 += v.z; s3 += v.w;
  }
  const int r = t >> 4;
  const int cq = (t & 15) * 4;
  lds[r][cq + 0] = s0; lds[r][cq + 1] = s1; lds[r][cq + 2] = s2; lds[r][cq + 3] = s3;
  __syncthreads();
  if (t < 64) {
    float tot = 0.f;
    #pragma unroll
    for (int rr = 0; rr < 16; ++rr) tot += lds[rr][t];
    unsafeAtomicAdd(&cs[t], tot);
  }
}

// ------------- fused: z = (x @ W) * rinv - cmW, bf16 out -------------
// x arrives pre-relu'd. cm computed during weight staging.
__global__ __launch_bounds__(256) void matnorm_kernel(
    const float* x, const float* __restrict__ W,
    const float* __restrict__ cs, unsigned short* __restrict__ z,
    int N, float invN) {
  const int lane = threadIdx.x & 63;
  const int wid  = blockIdx.x * (blockDim.x >> 6) + (threadIdx.x >> 6);
  const int nw   = gridDim.x * (blockDim.x >> 6);

  float w[64];
  float cm = 0.f;
  #pragma unroll
  for (int k = 0; k < 64; ++k) {
    w[k] = W[k * 64 + lane];
    cm = fmaf(cs[k], w[k], cm);    // cs[k] uniform scalar load
  }
  cm *= invN;

  for (int row = wid; row < N; row += nw) {
    const float xv = x[(size_t)row * 64 + lane];
    float ss = xv * xv;
    #pragma unroll
    for (int m = 1; m < 64; m <<= 1) ss += __shfl_xor(ss, m, 64);
    const float rinv = 1.0f / sqrtf(1e-6f + ss);
    float acc = 0.f;
    #pragma unroll
    for (int k = 0; k < 64; ++k) {
      const float xk = __builtin_bit_cast(
          float, __builtin_amdgcn_readlane(__builtin_bit_cast(int, xv), k));
      acc = fmaf(xk, w[k], acc);
    }
    z[(size_t)row * 64 + lane] = f2bf(acc * rinv - cm);
  }
}

// ------------- layer 3: z3 = x @ W3 (64->16), bf16 out (x pre-relu'd) -------------
__global__ __launch_bounds__(256) void mat16_kernel(
    const float* __restrict__ x, const float* __restrict__ W3,
    unsigned short* __restrict__ z3, int N) {
  const int lane = threadIdx.x & 63;
  const int j = lane & 15;
  const int wid = blockIdx.x * (blockDim.x >> 6) + (threadIdx.x >> 6);
  const int nw  = gridDim.x * (blockDim.x >> 6);

  float w[64];
  #pragma unroll
  for (int k = 0; k < 64; ++k) w[k] = W3[k * 16 + j];
  for (int row = wid; row < N; row += nw) {
    const float xv = x[(size_t)row * 64 + lane];
    float acc = 0.f;
    #pragma unroll
    for (int k = 0; k < 64; ++k) {
      const float xk = __builtin_bit_cast(
          float, __builtin_amdgcn_readlane(__builtin_bit_cast(int, xv), k));
      acc = fmaf(xk, w[k], acc);
    }
    if (lane < 16) z3[(size_t)row * 16 + lane] = f2bf(acc);
  }
}

// ================= CSR build: hi-bucket radix + LDS counting sort =================

__global__ void scanA_kernel(const int* __restrict__ cntA,
                             int* __restrict__ baseA, int* __restrict__ curA,
                             int NHI) {
  if (threadIdx.x == 0) {
    int acc = 0;
    for (int p = 0; p < NHI; ++p) { baseA[p] = acc; curA[p] = acc; acc += cntA[p]; }
    baseA[NHI] = acc;
  }
}

#define TILE 2048
#define CAPA 96   // per-tile per-bucket mean 42, sigma 6.4 -> 8.5 sigma headroom + spill
__global__ __launch_bounds__(256) void scatterA_kernel(
    const int* __restrict__ src, const int* __restrict__ dst,
    int* __restrict__ curA, int* __restrict__ psrc, int* __restrict__ pdst,
    int E) {
  __shared__ int lss[NHB][CAPA], ldd[NHB][CAPA];
  __shared__ int lcnt[NHB], lbase[NHB];
  const int t = threadIdx.x;
  if (t < NHB) lcnt[t] = 0;
  __syncthreads();
  const int ntiles = (E + TILE - 1) / TILE;
  for (int tile = blockIdx.x; tile < ntiles; tile += gridDim.x) {
    const int base = tile * TILE;
    #pragma unroll
    for (int j = 0; j < TILE / 256; ++j) {
      const int e = base + j * 256 + t;   // coalesced
      if (e < E) {
        const int d = __builtin_nontemporal_load(&dst[e]);
        const int s = __builtin_nontemporal_load(&src[e]);
        const int p = d >> 11;
        const int slot = atomicAdd(&lcnt[p], 1);
        if (slot < CAPA) { lss[p][slot] = s; ldd[p][slot] = d; }
        else {  // rare spill
          const int pos = atomicAdd(&curA[p], 1);
          psrc[pos] = s; pdst[pos] = d;
        }
      }
    }
    __syncthreads();
    if (t < NHB) {
      int c = lcnt[t]; if (c > CAPA) c = CAPA;
      lbase[t] = c ? atomicAdd(&curA[t], c) : 0;
      lcnt[t] = c;
    }
    __syncthreads();
    for (int p = 0; p < NHB; ++p) {
      const int c = lcnt[p];
      if (t < c) {  // c <= 96 < 256: one step, contiguous chunk
        psrc[lbase[p] + t] = lss[p][t];
        pdst[lbase[p] + t] = ldd[p][t];
      }
    }
    __syncthreads();
    if (t < NHB) lcnt[t] = 0;
    __syncthreads();
  }
}

// One workgroup (1024 thr) per hi-bucket: LDS counting sort of its ~32.7K
// edges by exact dst, coalesced csr + rowstart writes, 131 KB window on 1 CU.
__global__ __launch_bounds__(1024) void fillsort_kernel(
    const int* __restrict__ psrc, const int* __restrict__ pdst,
    const int* __restrict__ baseA, int* __restrict__ rowstart,
    int* __restrict__ csr, int N, int E) {
  __shared__ int hist[2048];
  __shared__ int bs[1024];
  const int t = threadIdx.x;
  const int h = blockIdx.x;
  const int nlo = h << 11;
  const int elo = baseA[h], ehi = baseA[h + 1];

  for (int i = t; i < 2048; i += 1024) hist[i] = 0;
  __syncthreads();

  // phase 1: histogram (4 independent loads in flight)
  int e = elo + t;
  for (; e + 3 * 1024 < ehi; e += 4 * 1024) {
    const int d0 = pdst[e], d1 = pdst[e + 1024],
              d2 = pdst[e + 2048], d3 = pdst[e + 3072];
    atomicAdd(&hist[d0 - nlo], 1); atomicAdd(&hist[d1 - nlo], 1);
    atomicAdd(&hist[d2 - nlo], 1); atomicAdd(&hist[d3 - nlo], 1);
  }
  for (; e < ehi; e += 1024) atomicAdd(&hist[pdst[e] - nlo], 1);
  __syncthreads();

  // exclusive scan of hist[2048] (2 per thread + 1024-wide Hillis-Steele)
  const int c0 = hist[2 * t], c1 = hist[2 * t + 1];
  const int s = c0 + c1;
  bs[t] = s;
  __syncthreads();
  for (int off = 1; off < 1024; off <<= 1) {
    const int v = (t >= off) ? bs[t - off] : 0;
    __syncthreads();
    bs[t] += v;
    __syncthreads();
  }
  const int excl = bs[t] - s;

  // rowstart + LDS cursors
  const int n0 = nlo + 2 * t;
  hist[2 * t] = excl;
  hist[2 * t + 1] = excl + c0;
  if (n0 < N)     rowstart[n0]     = elo + excl;
  if (n0 + 1 < N) rowstart[n0 + 1] = elo + excl + c0;
  if (h == 0 && t == 0) rowstart[N] = E;
  __syncthreads();

  // phase 2: place (all csr writes land in this bucket's 131 KB window)
  e = elo + t;
  for (; e + 3 * 1024 < ehi; e += 4 * 1024) {
    const int d0 = pdst[e],        s0 = psrc[e];
    const int d1 = pdst[e + 1024], s1 = psrc[e + 1024];
    const int d2 = pdst[e + 2048], s2 = psrc[e + 2048];
    const int d3 = pdst[e + 3072], s3 = psrc[e + 3072];
    csr[elo + atomicAdd(&hist[d0 - nlo], 1)] = s0;
    csr[elo + atomicAdd(&hist[d1 - nlo], 1)] = s1;
    csr[elo + atomicAdd(&hist[d2 - nlo], 1)] = s2;
    csr[elo + atomicAdd(&hist[d3 - nlo], 1)] = s3;
  }
  for (; e < ehi; e += 1024) {
    const int d = pdst[e], sv = psrc[e];
    csr[elo + atomicAdd(&hist[d - nlo], 1)] = sv;
  }
}

// ------- gather64: agg[d] = relu(z[d] + b + sum_{e in CSR[d]} z[src_e]) -------
// R8's proven form: one node per wave then exit; 16-deep flat ILP ladder;
// uniform scalar row base. relu on store (downstream reads pre-relu'd).
__global__ __launch_bounds__(256) void gather64_kernel(
    const unsigned short* __restrict__ z, const float* __restrict__ b,
    const int* __restrict__ rowstart, const int* __restrict__ csr,
    float* __restrict__ agg, int N) {
  const int lane = threadIdx.x & 63;
  int node = blockIdx.x * (blockDim.x >> 6) + (threadIdx.x >> 6);
  if (node >= N) return;
  node = __builtin_amdgcn_readfirstlane(node);  // wave-uniform -> scalar loads
  const int start = rowstart[node];
  const int end   = rowstart[node + 1];
  const unsigned short hs = z[(size_t)node * 64 + lane];  // self row, early issue
  float a0 = 0.f, a1 = 0.f, a2 = 0.f, a3 = 0.f;
  int e = start;
  for (; e + 16 <= end; e += 16) {   // 16 outstanding row loads
    unsigned short h[16];
    #pragma unroll
    for (int j = 0; j < 16; ++j) h[j] = z[(size_t)csr[e + j] * 64 + lane];
    #pragma unroll
    for (int j = 0; j < 16; j += 4) {
      a0 += bf2f(h[j + 0]); a1 += bf2f(h[j + 1]);
      a2 += bf2f(h[j + 2]); a3 += bf2f(h[j + 3]);
    }
  }
  for (; e + 4 <= end; e += 4) {     // 4-wide mid ladder
    unsigned short h[4];
    #pragma unroll
    for (int j = 0; j < 4; ++j) h[j] = z[(size_t)csr[e + j] * 64 + lane];
    a0 += bf2f(h[0]); a1 += bf2f(h[1]); a2 += bf2f(h[2]); a3 += bf2f(h[3]);
  }
  for (; e < end; ++e) a0 += bf2f(z[(size_t)csr[e] * 64 + lane]);
  const float sum = (a0 + a1) + (a2 + a3);
  agg[(size_t)node * 64 + lane] = fmaxf(bf2f(hs) + b[lane] + sum, 0.f);
}

// ------- gather16: out[d] = z3[d] + b3 + sum z3[src]; 16 feat x 4 edge-groups -------
__global__ __launch_bounds__(256) void gather16_kernel(
    const unsigned short* __restrict__ z3, const float* __restrict__ b3,
    const int* __restrict__ rowstart, const int* __restrict__ csr,
    float* __restrict__ out, int N) {
  const int lane = threadIdx.x & 63;
  const int f = lane & 15;
  const int g = lane >> 4;
  int node = blockIdx.x * (blockDim.x >> 6) + (threadIdx.x >> 6);
  if (node >= N) return;
  node = __builtin_amdgcn_readfirstlane(node);
  const int start = rowstart[node];
  const int end   = rowstart[node + 1];
  float acc0 = 0.f, acc1 = 0.f;
  int e = start + g;
  for (; e + 4 < end; e += 8) {      // 2 outstanding per lane-group
    acc0 += bf2f(z3[(size_t)csr[e] * 16 + f]);
    acc1 += bf2f(z3[(size_t)csr[e + 4] * 16 + f]);
  }
  if (e < end) acc0 += bf2f(z3[(size_t)csr[e] * 16 + f]);
  float acc = acc0 + acc1;
  acc += __shfl_xor(acc, 16, 64);
  acc += __shfl_xor(acc, 32, 64);
  if (lane < 16)
    out[(size_t)node * 16 + f] = bf2f(z3[(size_t)node * 16 + f]) + b3[f] + acc;
}

extern "C" void kernel_launch(void* const* d_in, const int* in_sizes, int n_in,
                              void* d_out, int out_size, void* d_ws, size_t ws_size,
                              hipStream_t stream) {
  const float* feat = (const float*)d_in[0];
  const float* W1 = (const float*)d_in[1];
  const float* b1 = (const float*)d_in[2];
  const float* W2 = (const float*)d_in[3];
  const float* b2 = (const float*)d_in[4];
  const float* W3 = (const float*)d_in[5];
  const float* b3 = (const float*)d_in[6];
  const int* src = (const int*)d_in[7];
  const int* dst = (const int*)d_in[8];
  const int N = in_sizes[0] / 64;
  const int E = in_sizes[7];
  float* out = (float*)d_out;

  // workspace layout
  float* B            = (float*)d_ws;                     // agg, N*64 fp32
  unsigned short* zb  = (unsigned short*)(B + (size_t)N * 64);  // z, N*64 bf16
  unsigned short* z3b = zb + (size_t)N * 64;              // z3, N*16 bf16
  int* cntA  = (int*)(z3b + (size_t)N * 16);              // NHB       } one memset
  float* cs1 = (float*)(cntA + NHB);                      // 64        } covers
  float* cs2 = cs1 + 64;                                  // 64        } these 3
  int* baseA    = (int*)(cs2 + 64);                       // NHB+1
  int* curA     = baseA + NHB + 1;                        // NHB
  int* rowstart = curA + NHB;                             // N+1
  int* csr      = rowstart + N + 1;                       // E
  // psrc/pdst alias zb+z3b (dead until matnorm/mat16): 2E ints = 12.8 MB <= 16 MB
  int* psrc = (int*)zb;
  int* pdst = psrc + E;

  const int NHI = (N + 2047) >> 11;     // 49
  const int node_blocks = (N + 3) / 4;  // 4 waves of 64 per block
  const float invN = 1.0f / (float)N;

  // ---- CSR build + layer-1 colsum ----
  hipMemsetAsync(cntA, 0, (NHB + 128) * sizeof(int), stream);  // cntA + cs1 + cs2
  prelude_kernel<<<512, 256, 0, stream>>>(dst, cntA, E, feat, cs1, N * 16);
  scanA_kernel<<<1, 64, 0, stream>>>(cntA, baseA, curA, NHI);
  scatterA_kernel<<<512, 256, 0, stream>>>(src, dst, curA, psrc, pdst, E);
  fillsort_kernel<<<NHI, 1024, 0, stream>>>(psrc, pdst, baseA, rowstart, csr, N, E);

  // ---- layer 1 (gather writes relu'd agg) ----
  matnorm_kernel<<<1024, 256, 0, stream>>>(feat, W1, cs1, zb, N, invN);
  gather64_kernel<<<node_blocks, 256, 0, stream>>>(zb, b1, rowstart, csr, B, N);

  // ---- layer 2 (B pre-relu'd) ----
  colsum_kernel<<<512, 256, 0, stream>>>(B, cs2, N * 16);
  matnorm_kernel<<<1024, 256, 0, stream>>>(B, W2, cs2, zb, N, invN);
  gather64_kernel<<<node_blocks, 256, 0, stream>>>(zb, b2, rowstart, csr, B, N);

  // ---- layer 3 (B pre-relu'd) ----
  mat16_kernel<<<1024, 256, 0, stream>>>(B, W3, z3b, N);
  gather16_kernel<<<node_blocks, 256, 0, stream>>>(z3b, b3, rowstart, csr, out, N);
}